// Round 15
// baseline (426.375 us; speedup 1.0000x reference)
//
#include <hip/hip_runtime.h>

#define IS2f 0.70710678118654752440f

// workspace offsets in floats
#define WS_Z   0ul          // 1024 * 2048
#define WS_G   2097152ul    // 1024 * 1024  (holds R, the Cholesky factor)
#define WS_H   3145728ul    // 1024 * 1024  (holds W = C C^T)
#define WS_SU  4194304ul    // 131072: [ci][b][j][c][l]
#define WS_VV  4325376ul    // 524288: [ci][b][j][l][n]
#define WS_B   4849664ul    // optional: 1024 * 8192 (32 MB)

#define WSYNC() asm volatile("" ::: "memory")

__device__ __forceinline__ float frcp(float v){ return __builtin_amdgcn_rcpf(v); }
__device__ __forceinline__ float frsq(float v){ return __builtin_amdgcn_rsqf(v); }
__device__ __forceinline__ float fsq (float v){ return __builtin_amdgcn_sqrtf(v); }
__device__ __forceinline__ float readlane_f(float v, int sl){
  return __uint_as_float(__builtin_amdgcn_readlane(__float_as_uint(v), sl));
}

__device__ __forceinline__ void decode_pid(int pid, int& ci, int& b, int& l, int& L){
  if (pid < 512)      { ci = 0; b = pid >> 7; l = pid & 127; L = 128; }
  else if (pid < 768) { int q = pid - 512; ci = 1; b = q >> 6; l = q & 63; L = 64; }
  else                { int q = pid - 768; ci = 2; b = q >> 6; l = q & 63; L = 64; }
}
__device__ __forceinline__ int su_base(int ci){ return ci==0 ? 0 : (ci==1 ? 65536 : 98304); }
__device__ __forceinline__ int vv_base(int ci){ return ci==0 ? 0 : (ci==1 ? 262144 : 393216); }
__device__ __forceinline__ int tpp(int r, int m){ return (m==0) ? r  : (r+m)%31; }
__device__ __forceinline__ int tqq(int r, int m){ return (m==0) ? 31 : (r+31-m)%31; }
// Jacobi rotation params (identical arithmetic everywhere)
__device__ __forceinline__ void jparam(float app, float aqq, float apq,
                                       float& cc, float& ss){
  float tau = (aqq - app) * frcp(2.f*apq);
  float tt  = ((tau>=0.f)?1.f:-1.f) * frcp(fabsf(tau) + fsq(fmaf(tau,tau,1.f)));
  float c   = frsq(fmaf(tt,tt,1.f));
  float s   = tt*c;
  bool ok = fabsf(apq) > 1e-28f;
  cc = ok ? c : 1.f;
  ss = ok ? s : 0.f;
}

// ---------------------------------------------------------------------------
// Kernel 1 (v5, unchanged from R12): 512 threads; G->Cholesky R in LDS,
// C = R^-T B register substitution, ws[WS_H] = W = C C^T.
// ---------------------------------------------------------------------------
#define PTS 260

__global__ __launch_bounds__(512) void k_fact(const float* __restrict__ x,
                                              const float* __restrict__ p,
                                              float* __restrict__ ws, int storeB){
  __shared__ __align__(16) float Ms[64*256];
  __shared__ __align__(16) float Zs[64*32];
  __shared__ __align__(16) float Pt[32*PTS];
  __shared__ __align__(16) float Bn[32*PTS];
  __shared__ float Gl[33*33];

  int pid = blockIdx.x, tid = threadIdx.x;
  int ci,b,l,L; decode_pid(pid,ci,b,l,L);

  {
    const float4* p4 = (const float4*)p;
    #pragma unroll
    for (int e=0;e<4;++e){
      int idx = tid + 512*e;
      int n = idx >> 3, k4 = idx & 7;
      float4 v = p4[idx];
      Pt[(4*k4+0)*PTS + n] = v.x;
      Pt[(4*k4+1)*PTS + n] = v.y;
      Pt[(4*k4+2)*PTS + n] = v.z;
      Pt[(4*k4+3)*PTS + n] = v.w;
    }
  }
  const float4* x4 = (const float4*)x;
  float4* Ms4 = (float4*)Ms;
  if (ci == 0){
    size_t base = ((size_t)(b*256 + 2*l) * 64) * 64;
    #pragma unroll
    for (int e=0;e<8;++e){
      int f = tid + 512*e;
      float4 A = x4[base + f];
      float4 Bv = x4[base + 4096 + f];
      float4 m;
      m.x=(A.x-Bv.x)*IS2f; m.y=(A.y-Bv.y)*IS2f; m.z=(A.z-Bv.z)*IS2f; m.w=(A.w-Bv.w)*IS2f;
      Ms4[f] = m;
    }
  } else {
    float sg = (ci==1) ? -0.5f : 0.5f;
    size_t base = ((size_t)(b*256 + 4*l) * 64) * 64;
    #pragma unroll
    for (int e=0;e<8;++e){
      int f = tid + 512*e;
      float4 A = x4[base + f];
      float4 B1 = x4[base + 4096 + f];
      float4 C1 = x4[base + 8192 + f];
      float4 D1 = x4[base + 12288 + f];
      float4 m;
      m.x=(A.x+B1.x)*0.5f + (C1.x+D1.x)*sg;
      m.y=(A.y+B1.y)*0.5f + (C1.y+D1.y)*sg;
      m.z=(A.z+B1.z)*0.5f + (C1.z+D1.z)*sg;
      m.w=(A.w+B1.w)*0.5f + (C1.w+D1.w)*sg;
      Ms4[f] = m;
    }
  }
  __syncthreads();

  {
    int k = tid & 31, c0 = tid >> 5;
    float acc[4] = {0,0,0,0};
    for (int n4=0;n4<64;++n4){
      float4 pv = *(const float4*)&Pt[k*PTS + 4*n4];
      #pragma unroll
      for (int i=0;i<4;++i){
        float4 m = Ms4[(c0*4+i)*64 + n4];
        acc[i] += m.x*pv.x + m.y*pv.y + m.z*pv.z + m.w*pv.w;
      }
    }
    #pragma unroll
    for (int i=0;i<4;++i){
      int c = c0*4 + i;
      Zs[c*32+k] = acc[i];
      ws[WS_Z + (size_t)pid*2048 + c*32 + k] = acc[i];
    }
  }
  __syncthreads();

  {
    int kk = tid & 31, j0 = tid >> 5;
    float ga[2] = {0,0};
    for (int c=0;c<64;++c){
      float zk = Zs[c*32+kk];
      #pragma unroll
      for (int e=0;e<2;++e) ga[e] += Zs[c*32 + j0 + 16*e] * zk;
    }
    #pragma unroll
    for (int e=0;e<2;++e)
      Gl[(j0+16*e)*33 + kk] = ga[e];
  }

  {
    int n4 = tid & 63, kg = tid >> 6;
    float4 facc[4];
    #pragma unroll
    for (int kq=0;kq<4;++kq){ facc[kq].x=0.f; facc[kq].y=0.f; facc[kq].z=0.f; facc[kq].w=0.f; }
    for (int c=0;c<64;++c){
      float4 mv = Ms4[c*64 + n4];
      float4 z1 = *(const float4*)&Zs[c*32 + kg*4];
      float zz[4] = {z1.x,z1.y,z1.z,z1.w};
      #pragma unroll
      for (int kq=0;kq<4;++kq){
        facc[kq].x += zz[kq]*mv.x; facc[kq].y += zz[kq]*mv.y;
        facc[kq].z += zz[kq]*mv.z; facc[kq].w += zz[kq]*mv.w;
      }
    }
    #pragma unroll
    for (int kq=0;kq<4;++kq){
      int krow = kg*4 + kq;
      *(float4*)&Bn[krow*PTS + 4*n4] = facc[kq];
      if (storeB)
        *(float4*)&ws[WS_B + (size_t)pid*8192 + (size_t)krow*256 + 4*n4] = facc[kq];
    }
  }
  __syncthreads();

  {
    int jlane = tid & 31, grp = tid >> 5;
    for (int k=0;k<32;++k){
      float gkk  = Gl[k*33+k];
      float ginv = frcp(gkk);
      float gkj  = Gl[k*33+jlane];
      float av[2], bv[2];
      #pragma unroll
      for (int e=0;e<2;++e){
        int i = k+1+grp+16*e; int ii = (i<32)? i : 31;
        av[e] = Gl[ii*33+jlane];
        bv[e] = Gl[k*33+ii];
      }
      WSYNC();
      #pragma unroll
      for (int e=0;e<2;++e){
        int i = k+1+grp+16*e;
        if (i < 32) Gl[i*33+jlane] = av[e] - bv[e]*gkj*ginv;
      }
      __syncthreads();
    }
    float sv[2];
    #pragma unroll
    for (int e=0;e<2;++e){
      int i = grp+16*e;
      sv[e] = Gl[i*33+jlane] * frsq(Gl[i*33+i]);
    }
    WSYNC();
    #pragma unroll
    for (int e=0;e<2;++e){
      int i = grp+16*e;
      Gl[i*33+jlane] = sv[e];
    }
  }
  __syncthreads();

  #pragma unroll
  for (int e=0;e<2;++e){
    int idx = tid + 512*e;
    ws[WS_G + (size_t)pid*1024 + idx] = Gl[(idx>>5)*33 + (idx&31)];
  }

  if (tid < 256){
    int n = tid;
    float c[32];
    #pragma unroll
    for (int i=0;i<32;++i){
      float cv = Bn[i*PTS + n];
      #pragma unroll
      for (int k=0;k<i;++k) cv -= Gl[k*33+i]*c[k];
      c[i] = cv * frcp(Gl[i*33+i]);
    }
    #pragma unroll
    for (int i=0;i<32;++i) Bn[i*PTS + n] = c[i];
  }
  __syncthreads();

  {
    int kk = tid & 31, j0 = tid >> 5;
    float h[2] = {0,0};
    for (int n4=0;n4<64;++n4){
      float4 bk = *(const float4*)&Bn[kk*PTS + 4*n4];
      #pragma unroll
      for (int e=0;e<2;++e){
        float4 bj = *(const float4*)&Bn[(j0+16*e)*PTS + 4*n4];
        h[e] += bj.x*bk.x + bj.y*bk.y + bj.z*bk.z + bj.w*bk.w;
      }
    }
    #pragma unroll
    for (int e=0;e<2;++e)
      ws[WS_H + (size_t)pid*1024 + (j0+16*e)*32 + kk] = h[e];
  }
}

// ---------------------------------------------------------------------------
// Kernel 2 (v8): double-buffered Jacobi — every H/V cell is rewritten each
// active round (16-pair tournament partitions rows AND cols), so round r
// reads buf[cur] and writes buf[cur^1]: reads can never conflict with
// writes -> ONE barrier per active round.  wave0 = col-pairs 0-7, wave1 =
// 8-15; V transposed (stride 36) updated with float4.
// ---------------------------------------------------------------------------
#define NSWEEP 5

__global__ __launch_bounds__(128) void k_solve(const float* __restrict__ x,
                                               float* __restrict__ ws, int useB){
  __shared__ float Gs[32*33];
  __shared__ float Hb[2][32*33];
  __shared__ __align__(16) float Vb[2][32*36];  // V^T: [col*36 + row]
  __shared__ float cA2[2][16], sA2[2][16];
  __shared__ float ggs[2][32];
  __shared__ float uss[2][64];

  int pid = blockIdx.x, tid = threadIdx.x;
  int wave = tid >> 6;
  int lane = tid & 63;
  int jlane = tid & 31;
  int hlf  = (tid >> 5) & 1;
  int ci,b,l,L; decode_pid(pid,ci,b,l,L);

  #pragma unroll
  for (int e=0;e<8;++e){
    int idx = tid + 128*e; int i = idx>>5, j = idx&31;
    Gs[i*33+j]    = ws[WS_G + (size_t)pid*1024 + idx];   // R
    Hb[0][i*33+j] = ws[WS_H + (size_t)pid*1024 + idx];   // W
  }
  #pragma unroll
  for (int e=0;e<9;++e) Vb[0][tid + 128*e] = 0.f;
  __syncthreads();
  if (tid < 32) Vb[0][tid*36 + tid] = 1.f;
  __syncthreads();

  // skip threshold (identical in both waves)
  float dmx = (lane < 32) ? fabsf(Hb[0][jlane*33+jlane]) : 0.f;
  #pragma unroll
  for (int off=1; off<64; off<<=1) dmx = fmaxf(dmx, __shfl_xor(dmx, off));
  float thr = dmx * 3e-6f;

  int m2 = (lane >> 3) + 8*wave;   // this lane's column-pair (0..15)
  int g  = lane & 7;               // worker / chunk index
  int cur = 0;

  for (int sw=0; sw<NSWEEP; ++sw){
    for (int r=0; r<31; ++r){
      float* Hc = Hb[cur];
      float* Hn = Hb[cur^1];
      float4* Vc4 = (float4*)Vb[cur];
      float4* Vn4 = (float4*)Vb[cur^1];

      // ---- read phase (all from cur buffers; no write conflicts possible)
      int m = lane & 15;
      int pm = tpp(r,m), qm = tqq(r,m);
      float apq = Hc[pm*33+qm];
      if (!__ballot(fabsf(apq) > thr)) continue;   // identical both waves
      float app = Hc[pm*33+pm];
      float aqq = Hc[qm*33+qm];
      float cc, ssv; jparam(app, aqq, apq, cc, ssv);
      if (lane < 16){ cA2[wave][lane] = cc; sA2[wave][lane] = ssv; }
      WSYNC();

      int p2 = tpp(r,m2), q2 = tqq(r,m2);
      float c2 = cA2[wave][m2], s2 = sA2[wave][m2];

      float a_[2], b_[2], c_[2], d_[2], c1v[2], s1v[2];
      int p1v[2], q1v[2];
      #pragma unroll
      for (int e=0;e<2;++e){
        int m1 = g + 8*e;
        int p1 = tpp(r,m1), q1 = tqq(r,m1);
        p1v[e]=p1; q1v[e]=q1;
        c1v[e]=cA2[wave][m1]; s1v[e]=sA2[wave][m1];
        a_[e] = Hc[p1*33+p2]; b_[e] = Hc[p1*33+q2];
        c_[e] = Hc[q1*33+p2]; d_[e] = Hc[q1*33+q2];
      }
      float4 vp = Vc4[p2*9 + g];
      float4 vq = Vc4[q2*9 + g];

      // ---- write phase (to alt buffers)
      #pragma unroll
      for (int e=0;e<2;++e){
        float c1 = c1v[e], s1 = s1v[e];
        float a1 = c1*a_[e] - s1*c_[e];
        float b1 = c1*b_[e] - s1*d_[e];
        float c1r= s1*a_[e] + c1*c_[e];
        float d1 = s1*b_[e] + c1*d_[e];
        Hn[p1v[e]*33+p2] = c2*a1 - s2*b1;
        Hn[p1v[e]*33+q2] = s2*a1 + c2*b1;
        Hn[q1v[e]*33+p2] = c2*c1r - s2*d1;
        Hn[q1v[e]*33+q2] = s2*c1r + c2*d1;
      }
      float4 np, nq;
      np.x = c2*vp.x - s2*vq.x;  nq.x = s2*vp.x + c2*vq.x;
      np.y = c2*vp.y - s2*vq.y;  nq.y = s2*vp.y + c2*vq.y;
      np.z = c2*vp.z - s2*vq.z;  nq.z = s2*vp.z + c2*vq.z;
      np.w = c2*vp.w - s2*vq.w;  nq.w = s2*vp.w + c2*vq.w;
      Vn4[p2*9 + g] = np;
      Vn4[q2*9 + g] = nq;
      __syncthreads();     // round end: all writes visible before next reads
      cur ^= 1;
    }
  }
  __syncthreads();
  if (wave == 1) return;

  float* Hs = Hb[cur];
  float* Vt = Vb[cur];

  // ================== epilogue: wave0 only ==================
  float rdgr = frcp(Gs[jlane*33+jlane]);

  float dv = (lane < 32) ? Hs[jlane*33+jlane] : -3e38f;
  float m1r = dv;
  #pragma unroll
  for (int off=1; off<64; off<<=1) m1r = fmaxf(m1r, __shfl_xor(m1r, off));
  unsigned long long bm = __ballot(dv == m1r);
  int i0 = __ffsll((unsigned long long)bm) - 1;
  float dv2 = (lane == i0) ? -3e38f : dv;
  float m2r = dv2;
  #pragma unroll
  for (int off=1; off<64; off<<=1) m2r = fmaxf(m2r, __shfl_xor(m2r, off));
  unsigned long long bm2 = __ballot(dv2 == m2r);
  int i1 = __ffsll((unsigned long long)bm2) - 1;

  float lam = hlf ? m2r : m1r;
  int   ti  = hlf ? i1 : i0;
  float sj  = fsq(fmaxf(lam, 0.f)); sj = fmaxf(sj, 1e-12f);
  float s0 = readlane_f(sj, 0);
  float s1 = readlane_f(sj, 32);

  // back-solve R g = w  (eigvec column ti lives at Vt[ti][*])
  {
    float rr = Vt[ti*36 + jlane];
    float Greg[32];
    #pragma unroll
    for (int i=0;i<32;++i) Greg[i] = Gs[jlane*33+i];
    #pragma unroll
    for (int i=31;i>=0;--i){
      float ri = __shfl(rr,  hlf*32 + i);
      float di = __shfl(rdgr, i);
      float g  = ri * di;
      if (jlane == i) ggs[hlf][i] = g;
      if (jlane < i)  rr -= Greg[i]*g;
    }
  }
  WSYNC();

  // u = Z g
  {
    const float4* Z4 = (const float4*)(ws + WS_Z + (size_t)pid*2048);
    float u0 = 0.f, u1 = 0.f;
    #pragma unroll
    for (int k4=0;k4<8;++k4){
      float4 z = Z4[lane*8 + k4];
      u0 += z.x*ggs[0][k4*4+0] + z.y*ggs[0][k4*4+1] + z.z*ggs[0][k4*4+2] + z.w*ggs[0][k4*4+3];
      u1 += z.x*ggs[1][k4*4+0] + z.y*ggs[1][k4*4+1] + z.z*ggs[1][k4*4+2] + z.w*ggs[1][k4*4+3];
    }
    uss[0][lane] = u0; uss[1][lane] = u1;
    ws[WS_SU + su_base(ci) + ((size_t)(b*2+0)*64 + lane)*L + l] = s0*u0;
    ws[WS_SU + su_base(ci) + ((size_t)(b*2+1)*64 + lane)*L + l] = s1*u1;
  }
  WSYNC();

  float i0s = frcp(s0), i1s = frcp(s1);
  size_t vb0 = WS_VV + vv_base(ci) + ((size_t)(b*2+0)*L + l)*256 + lane*4;
  size_t vb1 = WS_VV + vv_base(ci) + ((size_t)(b*2+1)*L + l)*256 + lane*4;

  if (useB){
    const float4* B4 = (const float4*)(ws + WS_B + (size_t)pid*8192);
    float a0x=0,a0y=0,a0z=0,a0w=0, a1x=0,a1y=0,a1z=0,a1w=0;
    #pragma unroll 8
    for (int k=0;k<32;++k){
      float4 bv = B4[(size_t)k*64 + lane];
      float g0 = ggs[0][k], g1 = ggs[1][k];
      a0x += g0*bv.x; a0y += g0*bv.y; a0z += g0*bv.z; a0w += g0*bv.w;
      a1x += g1*bv.x; a1y += g1*bv.y; a1z += g1*bv.z; a1w += g1*bv.w;
    }
    float4 r0; r0.x=a0x*i0s; r0.y=a0y*i0s; r0.z=a0z*i0s; r0.w=a0w*i0s;
    float4 r1; r1.x=a1x*i1s; r1.y=a1y*i1s; r1.z=a1z*i1s; r1.w=a1w*i1s;
    *(float4*)(ws + vb0) = r0;
    *(float4*)(ws + vb1) = r1;
  } else {
    float a0x=0,a0y=0,a0z=0,a0w=0, a1x=0,a1y=0,a1z=0,a1w=0;
    const float4* x4 = (const float4*)x;
    if (ci == 0){
      size_t base = ((size_t)(b*256 + 2*l) * 64) * 64;
      #pragma unroll 2
      for (int c=0;c<64;++c){
        float4 A  = x4[base + c*64 + lane];
        float4 Bv = x4[base + 4096 + c*64 + lane];
        float mx=(A.x-Bv.x)*IS2f, my=(A.y-Bv.y)*IS2f, mz=(A.z-Bv.z)*IS2f, mw=(A.w-Bv.w)*IS2f;
        float uc0 = uss[0][c], uc1 = uss[1][c];
        a0x += uc0*mx; a0y += uc0*my; a0z += uc0*mz; a0w += uc0*mw;
        a1x += uc1*mx; a1y += uc1*my; a1z += uc1*mz; a1w += uc1*mw;
      }
    } else {
      float sg = (ci==1) ? -0.5f : 0.5f;
      size_t base = ((size_t)(b*256 + 4*l) * 64) * 64;
      #pragma unroll 2
      for (int c=0;c<64;++c){
        float4 A  = x4[base + c*64 + lane];
        float4 B1 = x4[base + 4096 + c*64 + lane];
        float4 C1 = x4[base + 8192 + c*64 + lane];
        float4 D1 = x4[base + 12288 + c*64 + lane];
        float mx=(A.x+B1.x)*0.5f + (C1.x+D1.x)*sg;
        float my=(A.y+B1.y)*0.5f + (C1.y+D1.y)*sg;
        float mz=(A.z+B1.z)*0.5f + (C1.z+D1.z)*sg;
        float mw=(A.w+B1.w)*0.5f + (C1.w+D1.w)*sg;
        float uc0 = uss[0][c], uc1 = uss[1][c];
        a0x += uc0*mx; a0y += uc0*my; a0z += uc0*mz; a0w += uc0*mw;
        a1x += uc1*mx; a1y += uc1*my; a1z += uc1*mz; a1w += uc1*mw;
      }
    }
    ws[vb0+0]=a0x*i0s; ws[vb0+1]=a0y*i0s; ws[vb0+2]=a0z*i0s; ws[vb0+3]=a0w*i0s;
    ws[vb1+0]=a1x*i1s; ws[vb1+1]=a1y*i1s; ws[vb1+2]=a1z*i1s; ws[vb1+3]=a1w*i1s;
  }
}

// ---------------------------------------------------------------------------
// Kernel 3: writer (unchanged).
// ---------------------------------------------------------------------------
__global__ __launch_bounds__(256) void k_out(const float* __restrict__ x,
                                             const float* __restrict__ ws,
                                             float* __restrict__ out){
  __shared__ float d1[128*33];
  __shared__ float d2[64*33];
  __shared__ float a2s[64*33];
  __shared__ float Vs[2*128*33];
  __shared__ float Us[512];

  int nt = blockIdx.x, c = blockIdx.y, b = blockIdx.z;
  int n0 = nt * 32, tid = threadIdx.x;
  float* a1 = Vs;

  const float4* x4 = (const float4*)x;
  #pragma unroll
  for (int e=0;e<4;++e){
    int f = tid + 256*e; int l1 = f>>3, d4 = f&7;
    size_t r = ((size_t)(b*256 + 2*l1)*64 + c)*64 + (n0>>2) + d4;
    float4 A = x4[r], Bv = x4[r + 4096];
    int o = l1*33 + 4*d4;
    d1[o+0]=(A.x-Bv.x)*IS2f; d1[o+1]=(A.y-Bv.y)*IS2f; d1[o+2]=(A.z-Bv.z)*IS2f; d1[o+3]=(A.w-Bv.w)*IS2f;
    a1[o+0]=(A.x+Bv.x)*IS2f; a1[o+1]=(A.y+Bv.y)*IS2f; a1[o+2]=(A.z+Bv.z)*IS2f; a1[o+3]=(A.w+Bv.w)*IS2f;
  }
  __syncthreads();
  #pragma unroll
  for (int e=0;e<2;++e){
    int f = tid + 256*e; int l2 = f>>3, d4 = f&7;
    #pragma unroll
    for (int j=0;j<4;++j){
      int dn = 4*d4 + j;
      float aa = a1[(2*l2)*33 + dn], bb = a1[(2*l2+1)*33 + dn];
      d2[l2*33+dn]  = (aa-bb)*IS2f;
      a2s[l2*33+dn] = (aa+bb)*IS2f;
    }
  }
  #pragma unroll
  for (int e=0;e<2;++e){
    int idx = tid + 256*e;
    int j, l, L, so;
    if (idx < 256)      { j=idx>>7;        l=idx&127; L=128; so=0; }
    else if (idx < 384) { j=(idx-256)>>6;  l=idx&63;  L=64;  so=65536; }
    else                { j=(idx-384)>>6;  l=idx&63;  L=64;  so=98304; }
    Us[idx] = ws[WS_SU + so + ((size_t)(b*2+j)*64 + c)*L + l];
  }
  __syncthreads();

  for (int cc=0; cc<3; ++cc){
    int L   = (cc==0) ? 128 : 64;
    int pad = 256 - L;
    int sb  = cc*3;
    int uo  = (cc==0) ? 0 : (cc==1) ? 256 : 384;
    const float* cf = (cc==0) ? d1 : (cc==1) ? d2 : a2s;

    int iters = (2*L*32) >> 8;
    for (int e=0;e<iters;++e){
      int idx = tid + 256*e;
      int j = (idx >= L*32) ? 1 : 0;
      int rem = idx - j*L*32;
      int ll = rem >> 5, dn = rem & 31;
      Vs[j*4224 + ll*33 + dn] =
        ws[WS_VV + vv_base(cc) + ((size_t)(b*2+j)*L + ll)*256 + n0 + dn];
    }
    __syncthreads();

    int l = tid - pad;
    bool inr = (l >= 0);
    size_t obase = (size_t)sb*16777216 + (size_t)b*4194304 + (size_t)c*65536
                 + (size_t)n0*256 + tid;
    #pragma unroll 4
    for (int dn=0; dn<32; ++dn){
      float v0 = 0.f, v1 = 0.f, rv = 0.f;
      if (inr){
        float q0 = Us[uo + l]     * Vs[l*33 + dn];
        float q1 = Us[uo + L + l] * Vs[4224 + l*33 + dn];
        v0 = q0; v1 = q1;
        rv = cf[l*33 + dn] - q0 - q1;
      }
      out[obase + dn*256]            = v0;
      out[obase + dn*256 + 16777216] = v1;
      out[obase + dn*256 + 33554432] = rv;
    }
    __syncthreads();
  }
}

// ---------------------------------------------------------------------------
extern "C" void kernel_launch(void* const* d_in, const int* in_sizes, int n_in,
                              void* d_out, int out_size, void* d_ws, size_t ws_size,
                              hipStream_t stream) {
  const float* x = (const float*)d_in[0];
  const float* p = (const float*)d_in[1];
  float* out = (float*)d_out;
  float* ws  = (float*)d_ws;

  int useB = (ws_size >= (size_t)(WS_B + 1024ull*8192ull) * 4ull) ? 1 : 0;

  k_fact <<<1024, 512, 0, stream>>>(x, p, ws, useB);
  k_solve<<<1024, 128, 0, stream>>>(x, ws, useB);
  k_out  <<<dim3(8,64,4), 256, 0, stream>>>(x, ws, out);
}

// Round 16
// 400.581 us; speedup vs baseline: 1.0644x; 1.0644x over previous
//
#include <hip/hip_runtime.h>

#define IS2f 0.70710678118654752440f

// workspace offsets in floats
#define WS_Z   0ul          // 1024 * 2048
#define WS_G   2097152ul    // 1024 * 1024  (holds R, the Cholesky factor)
#define WS_H   3145728ul    // 1024 * 1024  (holds W = C C^T)
#define WS_SU  4194304ul    // 131072: [ci][b][j][c][l]
#define WS_VV  4325376ul    // 524288: [ci][b][j][l][n]
#define WS_B   4849664ul    // 1024 * 8192 (32 MB): holds C = R^-T B

#define WSYNC() asm volatile("" ::: "memory")

__device__ __forceinline__ float frcp(float v){ return __builtin_amdgcn_rcpf(v); }
__device__ __forceinline__ float frsq(float v){ return __builtin_amdgcn_rsqf(v); }
__device__ __forceinline__ float fsq (float v){ return __builtin_amdgcn_sqrtf(v); }
__device__ __forceinline__ float readlane_f(float v, int sl){
  return __uint_as_float(__builtin_amdgcn_readlane(__float_as_uint(v), sl));
}

__device__ __forceinline__ void decode_pid(int pid, int& ci, int& b, int& l, int& L){
  if (pid < 512)      { ci = 0; b = pid >> 7; l = pid & 127; L = 128; }
  else if (pid < 768) { int q = pid - 512; ci = 1; b = q >> 6; l = q & 63; L = 64; }
  else                { int q = pid - 768; ci = 2; b = q >> 6; l = q & 63; L = 64; }
}
__device__ __forceinline__ int su_base(int ci){ return ci==0 ? 0 : (ci==1 ? 65536 : 98304); }
__device__ __forceinline__ int vv_base(int ci){ return ci==0 ? 0 : (ci==1 ? 262144 : 393216); }
__device__ __forceinline__ int tpp(int r, int m){ return (m==0) ? r  : (r+m)%31; }
__device__ __forceinline__ int tqq(int r, int m){ return (m==0) ? 31 : (r+31-m)%31; }
// Jacobi rotation params (identical arithmetic everywhere)
__device__ __forceinline__ void jparam(float app, float aqq, float apq,
                                       float& cc, float& ss){
  float tau = (aqq - app) * frcp(2.f*apq);
  float tt  = ((tau>=0.f)?1.f:-1.f) * frcp(fabsf(tau) + fsq(fmaf(tau,tau,1.f)));
  float c   = frsq(fmaf(tt,tt,1.f));
  float s   = tt*c;
  bool ok = fabsf(apq) > 1e-28f;
  cc = ok ? c : 1.f;
  ss = ok ? s : 0.f;
}

// ---------------------------------------------------------------------------
// Kernel 1 (v6): 512 threads, LDS 76.4 KB -> 2 blocks/CU.
// p read directly from global (coalesced column loads, L1-resident).
// B stored to ws[WS_B]; C = R^-T B written to Cs (aliases Ms) + ws[WS_B].
// ws[WS_H] = W = C C^T from Cs.
// ---------------------------------------------------------------------------
#define PTS 260

__global__ __launch_bounds__(512, 4) void k_fact(const float* __restrict__ x,
                                                 const float* __restrict__ p,
                                                 float* __restrict__ ws, int storeB){
  __shared__ __align__(16) float Ms[64*256];   // 64 KB; aliased as Cs after B-pass
  __shared__ __align__(16) float Zs[64*32];    // 8 KB
  __shared__ float Gl[33*33];                  // 4.36 KB

  int pid = blockIdx.x, tid = threadIdx.x;
  int ci,b,l,L; decode_pid(pid,ci,b,l,L);

  // stage Ms with on-the-fly Haar
  const float4* x4 = (const float4*)x;
  float4* Ms4 = (float4*)Ms;
  if (ci == 0){
    size_t base = ((size_t)(b*256 + 2*l) * 64) * 64;
    #pragma unroll
    for (int e=0;e<8;++e){
      int f = tid + 512*e;
      float4 A = x4[base + f];
      float4 Bv = x4[base + 4096 + f];
      float4 m;
      m.x=(A.x-Bv.x)*IS2f; m.y=(A.y-Bv.y)*IS2f; m.z=(A.z-Bv.z)*IS2f; m.w=(A.w-Bv.w)*IS2f;
      Ms4[f] = m;
    }
  } else {
    float sg = (ci==1) ? -0.5f : 0.5f;
    size_t base = ((size_t)(b*256 + 4*l) * 64) * 64;
    #pragma unroll
    for (int e=0;e<8;++e){
      int f = tid + 512*e;
      float4 A = x4[base + f];
      float4 B1 = x4[base + 4096 + f];
      float4 C1 = x4[base + 8192 + f];
      float4 D1 = x4[base + 12288 + f];
      float4 m;
      m.x=(A.x+B1.x)*0.5f + (C1.x+D1.x)*sg;
      m.y=(A.y+B1.y)*0.5f + (C1.y+D1.y)*sg;
      m.z=(A.z+B1.z)*0.5f + (C1.z+D1.z)*sg;
      m.w=(A.w+B1.w)*0.5f + (C1.w+D1.w)*sg;
      Ms4[f] = m;
    }
  }
  __syncthreads();

  // ---- Z[c][k]: thread (k = tid&31, c0 = tid>>5), 4 c's each.
  // p column k read from global: lanes k=0..31 consecutive -> coalesced.
  {
    int k = tid & 31, c0 = tid >> 5;
    float acc[4] = {0,0,0,0};
    for (int n4=0;n4<64;++n4){
      float p0 = p[(4*n4+0)*32 + k];
      float p1 = p[(4*n4+1)*32 + k];
      float p2 = p[(4*n4+2)*32 + k];
      float p3 = p[(4*n4+3)*32 + k];
      #pragma unroll
      for (int i=0;i<4;++i){
        float4 m = Ms4[(c0*4+i)*64 + n4];
        acc[i] += m.x*p0 + m.y*p1 + m.z*p2 + m.w*p3;
      }
    }
    #pragma unroll
    for (int i=0;i<4;++i){
      int c = c0*4 + i;
      Zs[c*32+k] = acc[i];
      ws[WS_Z + (size_t)pid*2048 + c*32 + k] = acc[i];
    }
  }
  __syncthreads();

  // ---- G = Z^T Z into LDS (Gl)
  {
    int kk = tid & 31, j0 = tid >> 5;
    float ga[2] = {0,0};
    for (int c=0;c<64;++c){
      float zk = Zs[c*32+kk];
      #pragma unroll
      for (int e=0;e<2;++e) ga[e] += Zs[c*32 + j0 + 16*e] * zk;
    }
    #pragma unroll
    for (int e=0;e<2;++e)
      Gl[(j0+16*e)*33 + kk] = ga[e];
  }

  // ---- B[k][n]: thread (n4 = tid&63, kg = tid>>6), 4 k-rows; store to ws[WS_B]
  {
    int n4 = tid & 63, kg = tid >> 6;
    float4 facc[4];
    #pragma unroll
    for (int kq=0;kq<4;++kq){ facc[kq].x=0.f; facc[kq].y=0.f; facc[kq].z=0.f; facc[kq].w=0.f; }
    for (int c=0;c<64;++c){
      float4 mv = Ms4[c*64 + n4];
      float4 z1 = *(const float4*)&Zs[c*32 + kg*4];
      float zz[4] = {z1.x,z1.y,z1.z,z1.w};
      #pragma unroll
      for (int kq=0;kq<4;++kq){
        facc[kq].x += zz[kq]*mv.x; facc[kq].y += zz[kq]*mv.y;
        facc[kq].z += zz[kq]*mv.z; facc[kq].w += zz[kq]*mv.w;
      }
    }
    #pragma unroll
    for (int kq=0;kq<4;++kq){
      int krow = kg*4 + kq;
      *(float4*)&ws[WS_B + (size_t)pid*8192 + (size_t)krow*256 + 4*n4] = facc[kq];
    }
  }
  __syncthreads();   // B stores drained (vmcnt(0) before s_barrier); Ms now dead

  // ---- Cholesky of Gl (right-looking, deferred scaling; 1 barrier/step)
  {
    int jlane = tid & 31, grp = tid >> 5;
    for (int k=0;k<32;++k){
      float gkk  = Gl[k*33+k];
      float ginv = frcp(gkk);
      float gkj  = Gl[k*33+jlane];
      float av[2], bv[2];
      #pragma unroll
      for (int e=0;e<2;++e){
        int i = k+1+grp+16*e; int ii = (i<32)? i : 31;
        av[e] = Gl[ii*33+jlane];
        bv[e] = Gl[k*33+ii];
      }
      WSYNC();
      #pragma unroll
      for (int e=0;e<2;++e){
        int i = k+1+grp+16*e;
        if (i < 32) Gl[i*33+jlane] = av[e] - bv[e]*gkj*ginv;
      }
      __syncthreads();
    }
    float sv[2];
    #pragma unroll
    for (int e=0;e<2;++e){
      int i = grp+16*e;
      sv[e] = Gl[i*33+jlane] * frsq(Gl[i*33+i]);
    }
    WSYNC();
    #pragma unroll
    for (int e=0;e<2;++e){
      int i = grp+16*e;
      Gl[i*33+jlane] = sv[e];
    }
  }
  __syncthreads();

  // ---- store R to ws[WS_G]
  #pragma unroll
  for (int e=0;e<2;++e){
    int idx = tid + 512*e;
    ws[WS_G + (size_t)pid*1024 + idx] = Gl[(idx>>5)*33 + (idx&31)];
  }

  // ---- C = R^-T B: column-parallel forward substitution.
  // B column from global (coalesced); C written to Cs (alias of Ms, stride
  // PTS) and back to ws[WS_B].
  float* Cs = Ms;
  if (tid < 256){
    int n = tid;
    float bcol[32];
    #pragma unroll
    for (int i=0;i<32;++i)
      bcol[i] = ws[WS_B + (size_t)pid*8192 + (size_t)i*256 + n];
    float c[32];
    #pragma unroll
    for (int i=0;i<32;++i){
      float cv = bcol[i];
      #pragma unroll
      for (int k=0;k<i;++k) cv -= Gl[k*33+i]*c[k];
      c[i] = cv * frcp(Gl[i*33+i]);
    }
    #pragma unroll
    for (int i=0;i<32;++i){
      Cs[i*PTS + n] = c[i];
      ws[WS_B + (size_t)pid*8192 + (size_t)i*256 + n] = c[i];
    }
  }
  __syncthreads();

  // ---- W = C C^T from Cs -> ws[WS_H]
  {
    int kk = tid & 31, j0 = tid >> 5;
    float h[2] = {0,0};
    for (int n4=0;n4<64;++n4){
      float4 bk = *(const float4*)&Cs[kk*PTS + 4*n4];
      #pragma unroll
      for (int e=0;e<2;++e){
        float4 bj = *(const float4*)&Cs[(j0+16*e)*PTS + 4*n4];
        h[e] += bj.x*bk.x + bj.y*bk.y + bj.z*bk.z + bj.w*bk.w;
      }
    }
    #pragma unroll
    for (int e=0;e<2;++e)
      ws[WS_H + (size_t)pid*1024 + (j0+16*e)*32 + kk] = h[e];
  }
}

// ---------------------------------------------------------------------------
// Kernel 2 (v9): Jacobi = R15's double-buffered scheme (unchanged).
// Epilogue vh = (w^T C)/s using C at ws[WS_B] (w = Jacobi eigvec).
// ---------------------------------------------------------------------------
#define NSWEEP 5

__global__ __launch_bounds__(128) void k_solve(const float* __restrict__ x,
                                               float* __restrict__ ws, int useB){
  __shared__ float Gs[32*33];
  __shared__ float Hb[2][32*33];
  __shared__ __align__(16) float Vb[2][32*36];  // V^T: [col*36 + row]
  __shared__ float cA2[2][16], sA2[2][16];
  __shared__ float ggs[2][32];
  __shared__ float wws[2][32];
  __shared__ float uss[2][64];

  int pid = blockIdx.x, tid = threadIdx.x;
  int wave = tid >> 6;
  int lane = tid & 63;
  int jlane = tid & 31;
  int hlf  = (tid >> 5) & 1;
  int ci,b,l,L; decode_pid(pid,ci,b,l,L);

  #pragma unroll
  for (int e=0;e<8;++e){
    int idx = tid + 128*e; int i = idx>>5, j = idx&31;
    Gs[i*33+j]    = ws[WS_G + (size_t)pid*1024 + idx];   // R
    Hb[0][i*33+j] = ws[WS_H + (size_t)pid*1024 + idx];   // W
  }
  #pragma unroll
  for (int e=0;e<9;++e) Vb[0][tid + 128*e] = 0.f;
  __syncthreads();
  if (tid < 32) Vb[0][tid*36 + tid] = 1.f;
  __syncthreads();

  // skip threshold (identical in both waves)
  float dmx = (lane < 32) ? fabsf(Hb[0][jlane*33+jlane]) : 0.f;
  #pragma unroll
  for (int off=1; off<64; off<<=1) dmx = fmaxf(dmx, __shfl_xor(dmx, off));
  float thr = dmx * 3e-6f;

  int m2 = (lane >> 3) + 8*wave;   // this lane's column-pair (0..15)
  int g  = lane & 7;               // worker / chunk index
  int cur = 0;

  for (int sw=0; sw<NSWEEP; ++sw){
    for (int r=0; r<31; ++r){
      float* Hc = Hb[cur];
      float* Hn = Hb[cur^1];
      float4* Vc4 = (float4*)Vb[cur];
      float4* Vn4 = (float4*)Vb[cur^1];

      int m = lane & 15;
      int pm = tpp(r,m), qm = tqq(r,m);
      float apq = Hc[pm*33+qm];
      if (!__ballot(fabsf(apq) > thr)) continue;
      float app = Hc[pm*33+pm];
      float aqq = Hc[qm*33+qm];
      float cc, ssv; jparam(app, aqq, apq, cc, ssv);
      if (lane < 16){ cA2[wave][lane] = cc; sA2[wave][lane] = ssv; }
      WSYNC();

      int p2 = tpp(r,m2), q2 = tqq(r,m2);
      float c2 = cA2[wave][m2], s2 = sA2[wave][m2];

      float a_[2], b_[2], c_[2], d_[2], c1v[2], s1v[2];
      int p1v[2], q1v[2];
      #pragma unroll
      for (int e=0;e<2;++e){
        int m1 = g + 8*e;
        int p1 = tpp(r,m1), q1 = tqq(r,m1);
        p1v[e]=p1; q1v[e]=q1;
        c1v[e]=cA2[wave][m1]; s1v[e]=sA2[wave][m1];
        a_[e] = Hc[p1*33+p2]; b_[e] = Hc[p1*33+q2];
        c_[e] = Hc[q1*33+p2]; d_[e] = Hc[q1*33+q2];
      }
      float4 vp = Vc4[p2*9 + g];
      float4 vq = Vc4[q2*9 + g];

      #pragma unroll
      for (int e=0;e<2;++e){
        float c1 = c1v[e], s1 = s1v[e];
        float a1 = c1*a_[e] - s1*c_[e];
        float b1 = c1*b_[e] - s1*d_[e];
        float c1r= s1*a_[e] + c1*c_[e];
        float d1 = s1*b_[e] + c1*d_[e];
        Hn[p1v[e]*33+p2] = c2*a1 - s2*b1;
        Hn[p1v[e]*33+q2] = s2*a1 + c2*b1;
        Hn[q1v[e]*33+p2] = c2*c1r - s2*d1;
        Hn[q1v[e]*33+q2] = s2*c1r + c2*d1;
      }
      float4 np, nq;
      np.x = c2*vp.x - s2*vq.x;  nq.x = s2*vp.x + c2*vq.x;
      np.y = c2*vp.y - s2*vq.y;  nq.y = s2*vp.y + c2*vq.y;
      np.z = c2*vp.z - s2*vq.z;  nq.z = s2*vp.z + c2*vq.z;
      np.w = c2*vp.w - s2*vq.w;  nq.w = s2*vp.w + c2*vq.w;
      Vn4[p2*9 + g] = np;
      Vn4[q2*9 + g] = nq;
      __syncthreads();
      cur ^= 1;
    }
  }
  __syncthreads();
  if (wave == 1) return;

  float* Hs = Hb[cur];
  float* Vt = Vb[cur];

  // ================== epilogue: wave0 only ==================
  float rdgr = frcp(Gs[jlane*33+jlane]);

  float dv = (lane < 32) ? Hs[jlane*33+jlane] : -3e38f;
  float m1r = dv;
  #pragma unroll
  for (int off=1; off<64; off<<=1) m1r = fmaxf(m1r, __shfl_xor(m1r, off));
  unsigned long long bm = __ballot(dv == m1r);
  int i0 = __ffsll((unsigned long long)bm) - 1;
  float dv2 = (lane == i0) ? -3e38f : dv;
  float m2r = dv2;
  #pragma unroll
  for (int off=1; off<64; off<<=1) m2r = fmaxf(m2r, __shfl_xor(m2r, off));
  unsigned long long bm2 = __ballot(dv2 == m2r);
  int i1 = __ffsll((unsigned long long)bm2) - 1;

  float lam = hlf ? m2r : m1r;
  int   ti  = hlf ? i1 : i0;
  float sj  = fsq(fmaxf(lam, 0.f)); sj = fmaxf(sj, 1e-12f);
  float s0 = readlane_f(sj, 0);
  float s1 = readlane_f(sj, 32);

  // back-solve R g = w  (w stored to wws for the C-epilogue)
  {
    float rr = Vt[ti*36 + jlane];
    wws[hlf][jlane] = rr;
    float Greg[32];
    #pragma unroll
    for (int i=0;i<32;++i) Greg[i] = Gs[jlane*33+i];
    #pragma unroll
    for (int i=31;i>=0;--i){
      float ri = __shfl(rr,  hlf*32 + i);
      float di = __shfl(rdgr, i);
      float g  = ri * di;
      if (jlane == i) ggs[hlf][i] = g;
      if (jlane < i)  rr -= Greg[i]*g;
    }
  }
  WSYNC();

  // u = Z g
  {
    const float4* Z4 = (const float4*)(ws + WS_Z + (size_t)pid*2048);
    float u0 = 0.f, u1 = 0.f;
    #pragma unroll
    for (int k4=0;k4<8;++k4){
      float4 z = Z4[lane*8 + k4];
      u0 += z.x*ggs[0][k4*4+0] + z.y*ggs[0][k4*4+1] + z.z*ggs[0][k4*4+2] + z.w*ggs[0][k4*4+3];
      u1 += z.x*ggs[1][k4*4+0] + z.y*ggs[1][k4*4+1] + z.z*ggs[1][k4*4+2] + z.w*ggs[1][k4*4+3];
    }
    uss[0][lane] = u0; uss[1][lane] = u1;
    ws[WS_SU + su_base(ci) + ((size_t)(b*2+0)*64 + lane)*L + l] = s0*u0;
    ws[WS_SU + su_base(ci) + ((size_t)(b*2+1)*64 + lane)*L + l] = s1*u1;
  }
  WSYNC();

  float i0s = frcp(s0), i1s = frcp(s1);
  size_t vb0 = WS_VV + vv_base(ci) + ((size_t)(b*2+0)*L + l)*256 + lane*4;
  size_t vb1 = WS_VV + vv_base(ci) + ((size_t)(b*2+1)*L + l)*256 + lane*4;

  if (useB){
    // vh_j = (w_j^T C) / s_j   (C at ws[WS_B]; g^T B == w^T C exactly)
    const float4* C4 = (const float4*)(ws + WS_B + (size_t)pid*8192);
    float a0x=0,a0y=0,a0z=0,a0w=0, a1x=0,a1y=0,a1z=0,a1w=0;
    #pragma unroll 8
    for (int k=0;k<32;++k){
      float4 cv = C4[(size_t)k*64 + lane];
      float w0 = wws[0][k], w1 = wws[1][k];
      a0x += w0*cv.x; a0y += w0*cv.y; a0z += w0*cv.z; a0w += w0*cv.w;
      a1x += w1*cv.x; a1y += w1*cv.y; a1z += w1*cv.z; a1w += w1*cv.w;
    }
    float4 r0; r0.x=a0x*i0s; r0.y=a0y*i0s; r0.z=a0z*i0s; r0.w=a0w*i0s;
    float4 r1; r1.x=a1x*i1s; r1.y=a1y*i1s; r1.z=a1z*i1s; r1.w=a1w*i1s;
    *(float4*)(ws + vb0) = r0;
    *(float4*)(ws + vb1) = r1;
  } else {
    // fallback: vh_j = u_j^T M / s_j, streaming x
    float a0x=0,a0y=0,a0z=0,a0w=0, a1x=0,a1y=0,a1z=0,a1w=0;
    const float4* x4 = (const float4*)x;
    if (ci == 0){
      size_t base = ((size_t)(b*256 + 2*l) * 64) * 64;
      #pragma unroll 2
      for (int c=0;c<64;++c){
        float4 A  = x4[base + c*64 + lane];
        float4 Bv = x4[base + 4096 + c*64 + lane];
        float mx=(A.x-Bv.x)*IS2f, my=(A.y-Bv.y)*IS2f, mz=(A.z-Bv.z)*IS2f, mw=(A.w-Bv.w)*IS2f;
        float uc0 = uss[0][c], uc1 = uss[1][c];
        a0x += uc0*mx; a0y += uc0*my; a0z += uc0*mz; a0w += uc0*mw;
        a1x += uc1*mx; a1y += uc1*my; a1z += uc1*mz; a1w += uc1*mw;
      }
    } else {
      float sg = (ci==1) ? -0.5f : 0.5f;
      size_t base = ((size_t)(b*256 + 4*l) * 64) * 64;
      #pragma unroll 2
      for (int c=0;c<64;++c){
        float4 A  = x4[base + c*64 + lane];
        float4 B1 = x4[base + 4096 + c*64 + lane];
        float4 C1 = x4[base + 8192 + c*64 + lane];
        float4 D1 = x4[base + 12288 + c*64 + lane];
        float mx=(A.x+B1.x)*0.5f + (C1.x+D1.x)*sg;
        float my=(A.y+B1.y)*0.5f + (C1.y+D1.y)*sg;
        float mz=(A.z+B1.z)*0.5f + (C1.z+D1.z)*sg;
        float mw=(A.w+B1.w)*0.5f + (C1.w+D1.w)*sg;
        float uc0 = uss[0][c], uc1 = uss[1][c];
        a0x += uc0*mx; a0y += uc0*my; a0z += uc0*mz; a0w += uc0*mw;
        a1x += uc1*mx; a1y += uc1*my; a1z += uc1*mz; a1w += uc1*mw;
      }
    }
    ws[vb0+0]=a0x*i0s; ws[vb0+1]=a0y*i0s; ws[vb0+2]=a0z*i0s; ws[vb0+3]=a0w*i0s;
    ws[vb1+0]=a1x*i1s; ws[vb1+1]=a1y*i1s; ws[vb1+2]=a1z*i1s; ws[vb1+3]=a1w*i1s;
  }
}

// ---------------------------------------------------------------------------
// Kernel 3: writer (unchanged).
// ---------------------------------------------------------------------------
__global__ __launch_bounds__(256) void k_out(const float* __restrict__ x,
                                             const float* __restrict__ ws,
                                             float* __restrict__ out){
  __shared__ float d1[128*33];
  __shared__ float d2[64*33];
  __shared__ float a2s[64*33];
  __shared__ float Vs[2*128*33];
  __shared__ float Us[512];

  int nt = blockIdx.x, c = blockIdx.y, b = blockIdx.z;
  int n0 = nt * 32, tid = threadIdx.x;
  float* a1 = Vs;

  const float4* x4 = (const float4*)x;
  #pragma unroll
  for (int e=0;e<4;++e){
    int f = tid + 256*e; int l1 = f>>3, d4 = f&7;
    size_t r = ((size_t)(b*256 + 2*l1)*64 + c)*64 + (n0>>2) + d4;
    float4 A = x4[r], Bv = x4[r + 4096];
    int o = l1*33 + 4*d4;
    d1[o+0]=(A.x-Bv.x)*IS2f; d1[o+1]=(A.y-Bv.y)*IS2f; d1[o+2]=(A.z-Bv.z)*IS2f; d1[o+3]=(A.w-Bv.w)*IS2f;
    a1[o+0]=(A.x+Bv.x)*IS2f; a1[o+1]=(A.y+Bv.y)*IS2f; a1[o+2]=(A.z+Bv.z)*IS2f; a1[o+3]=(A.w+Bv.w)*IS2f;
  }
  __syncthreads();
  #pragma unroll
  for (int e=0;e<2;++e){
    int f = tid + 256*e; int l2 = f>>3, d4 = f&7;
    #pragma unroll
    for (int j=0;j<4;++j){
      int dn = 4*d4 + j;
      float aa = a1[(2*l2)*33 + dn], bb = a1[(2*l2+1)*33 + dn];
      d2[l2*33+dn]  = (aa-bb)*IS2f;
      a2s[l2*33+dn] = (aa+bb)*IS2f;
    }
  }
  #pragma unroll
  for (int e=0;e<2;++e){
    int idx = tid + 256*e;
    int j, l, L, so;
    if (idx < 256)      { j=idx>>7;        l=idx&127; L=128; so=0; }
    else if (idx < 384) { j=(idx-256)>>6;  l=idx&63;  L=64;  so=65536; }
    else                { j=(idx-384)>>6;  l=idx&63;  L=64;  so=98304; }
    Us[idx] = ws[WS_SU + so + ((size_t)(b*2+j)*64 + c)*L + l];
  }
  __syncthreads();

  for (int cc=0; cc<3; ++cc){
    int L   = (cc==0) ? 128 : 64;
    int pad = 256 - L;
    int sb  = cc*3;
    int uo  = (cc==0) ? 0 : (cc==1) ? 256 : 384;
    const float* cf = (cc==0) ? d1 : (cc==1) ? d2 : a2s;

    int iters = (2*L*32) >> 8;
    for (int e=0;e<iters;++e){
      int idx = tid + 256*e;
      int j = (idx >= L*32) ? 1 : 0;
      int rem = idx - j*L*32;
      int ll = rem >> 5, dn = rem & 31;
      Vs[j*4224 + ll*33 + dn] =
        ws[WS_VV + vv_base(cc) + ((size_t)(b*2+j)*L + ll)*256 + n0 + dn];
    }
    __syncthreads();

    int l = tid - pad;
    bool inr = (l >= 0);
    size_t obase = (size_t)sb*16777216 + (size_t)b*4194304 + (size_t)c*65536
                 + (size_t)n0*256 + tid;
    #pragma unroll 4
    for (int dn=0; dn<32; ++dn){
      float v0 = 0.f, v1 = 0.f, rv = 0.f;
      if (inr){
        float q0 = Us[uo + l]     * Vs[l*33 + dn];
        float q1 = Us[uo + L + l] * Vs[4224 + l*33 + dn];
        v0 = q0; v1 = q1;
        rv = cf[l*33 + dn] - q0 - q1;
      }
      out[obase + dn*256]            = v0;
      out[obase + dn*256 + 16777216] = v1;
      out[obase + dn*256 + 33554432] = rv;
    }
    __syncthreads();
  }
}

// ---------------------------------------------------------------------------
extern "C" void kernel_launch(void* const* d_in, const int* in_sizes, int n_in,
                              void* d_out, int out_size, void* d_ws, size_t ws_size,
                              hipStream_t stream) {
  const float* x = (const float*)d_in[0];
  const float* p = (const float*)d_in[1];
  float* out = (float*)d_out;
  float* ws  = (float*)d_ws;

  int useB = (ws_size >= (size_t)(WS_B + 1024ull*8192ull) * 4ull) ? 1 : 0;

  k_fact <<<1024, 512, 0, stream>>>(x, p, ws, useB);
  k_solve<<<1024, 128, 0, stream>>>(x, ws, useB);
  k_out  <<<dim3(8,64,4), 256, 0, stream>>>(x, ws, out);
}